// Round 4
// baseline (806.221 us; speedup 1.0000x reference)
//
#include <hip/hip_runtime.h>
#include <hip/hip_bf16.h>

#define DIN 128
#define DH  128
#define DOUT 64
#define BSHIFT 6                 // 64 nodes per bucket

typedef __attribute__((ext_vector_type(8))) short short8;
typedef __attribute__((ext_vector_type(4))) float f32x4;

static __device__ __forceinline__ unsigned short f2bf(float f) {
    unsigned int u = __float_as_uint(f);
    u += 0x7FFFu + ((u >> 16) & 1u);   // RNE
    return (unsigned short)(u >> 16);
}
static __device__ __forceinline__ float bflo(unsigned int p) {   // low bf16 of packed pair
    return __uint_as_float(p << 16);
}
static __device__ __forceinline__ float bfhi(unsigned int p) {   // high bf16 of packed pair
    return __uint_as_float(p & 0xFFFF0000u);
}

// ---------------- cast fp32 -> bf16 (vectorized) ----------------
__global__ __launch_bounds__(256) void cast_bf16_kernel(const float* __restrict__ x,
                                                        unsigned short* __restrict__ o, int n4) {
    int i = blockIdx.x * 256 + threadIdx.x;
    if (i >= n4) return;
    float4 v = ((const float4*)x)[i];
    ushort4 r;
    r.x = f2bf(v.x); r.y = f2bf(v.y); r.z = f2bf(v.z); r.w = f2bf(v.w);
    ((ushort4*)o)[i] = r;
}

// ---------------- weights: transpose + cast to bf16 ----------------
__global__ __launch_bounds__(256) void prep_w_kernel(const float* __restrict__ W1,
                                                     const float* __restrict__ W2,
                                                     const float* __restrict__ W3,
                                                     unsigned short* __restrict__ Wt1,
                                                     unsigned short* __restrict__ Wt2,
                                                     unsigned short* __restrict__ Wt3) {
    int i = blockIdx.x * 256 + threadIdx.x;
    if (i < 128 * 128) {
        int n = i >> 7, k = i & 127;
        Wt1[n * 128 + k] = f2bf(W1[k * 128 + n]);
        Wt2[n * 128 + k] = f2bf(W2[k * 128 + n]);
        if (n < 64) Wt3[n * 128 + k] = f2bf(W3[k * 64 + n]);
    }
}

// ---------------- degree ----------------
__global__ __launch_bounds__(256) void deg_init_kernel(int* __restrict__ deg, int n) {
    int i = blockIdx.x * 256 + threadIdx.x;
    if (i < n) deg[i] = 1;   // self-loop
}
__global__ __launch_bounds__(256) void deg_count_kernel(const int* __restrict__ ei, int E,
                                                        int* __restrict__ deg) {
    int e = blockIdx.x * 256 + threadIdx.x;
    if (e >= E) return;
    atomicAdd(&deg[ei[E + e]], 1);   // dst
}

// ---------------- 3-phase exclusive scan of deg -> row_start ----------------
__global__ __launch_bounds__(256) void scan_block_sums(const int* __restrict__ deg,
                                                       int* __restrict__ bsum, int n) {
    __shared__ int s[256];
    int t = threadIdx.x, base = blockIdx.x * 1024;
    int v = 0;
    #pragma unroll
    for (int j = 0; j < 4; j++) {
        int idx = base + t * 4 + j;
        if (idx < n) v += deg[idx];
    }
    s[t] = v; __syncthreads();
    for (int off = 128; off > 0; off >>= 1) {
        if (t < off) s[t] += s[t + off];
        __syncthreads();
    }
    if (t == 0) bsum[blockIdx.x] = s[0];
}

__global__ __launch_bounds__(256) void scan_bsum_kernel(int* __restrict__ bsum, int nb) {
    __shared__ int s[256];
    int t = threadIdx.x;
    s[t] = (t < nb) ? bsum[t] : 0; __syncthreads();
    for (int off = 1; off < 256; off <<= 1) {
        int v = (t >= off) ? s[t - off] : 0;
        __syncthreads();
        s[t] += v;
        __syncthreads();
    }
    if (t < nb) bsum[t] = (t > 0) ? s[t - 1] : 0;   // exclusive
}

__global__ __launch_bounds__(256) void scan_final_kernel(const int* __restrict__ deg,
                                                         const int* __restrict__ bsum_ex,
                                                         int* __restrict__ row_start,
                                                         float* __restrict__ dis,
                                                         int2* __restrict__ csr_pk, int n) {
    __shared__ int s[256];
    int t = threadIdx.x, base = blockIdx.x * 1024;
    int d[4]; int local = 0;
    #pragma unroll
    for (int j = 0; j < 4; j++) {
        int idx = base + t * 4 + j;
        d[j] = (idx < n) ? deg[idx] : 0;
        local += d[j];
    }
    s[t] = local; __syncthreads();
    for (int off = 1; off < 256; off <<= 1) {
        int v = (t >= off) ? s[t - off] : 0;
        __syncthreads();
        s[t] += v;
        __syncthreads();
    }
    int ex = ((t > 0) ? s[t - 1] : 0) + bsum_ex[blockIdx.x];
    #pragma unroll
    for (int j = 0; j < 4; j++) {
        int idx = base + t * 4 + j;
        if (idx < n) {
            row_start[idx] = ex;
            float di = rsqrtf((float)d[j]);
            dis[idx] = di;
            int2 pk; pk.x = idx; pk.y = __float_as_int(di * di);
            csr_pk[ex] = pk;               // slot 0 = self loop
            if (idx == n - 1) row_start[n] = ex + d[j];
            ex += d[j];
        }
    }
}

// ---------------- bucketed counting sort ----------------
// bucket b covers nodes [b*64, (b+1)*64); staging offset = row_start[b*64] - b*64
__global__ __launch_bounds__(256) void bcur_init_kernel(const int* __restrict__ row_start,
                                                        int* __restrict__ bcur, int nbuk, int n) {
    int b = blockIdx.x * 256 + threadIdx.x;
    if (b > nbuk) return;
    int v = min(b << BSHIFT, n);
    bcur[b] = row_start[v] - v;
}

// Pass A: append {src,dst} into bucket staging segments (sequential per bucket)
__global__ __launch_bounds__(256) void stage_kernel(const int* __restrict__ ei, int E,
                                                    int* __restrict__ bcur,
                                                    int2* __restrict__ staged) {
    int e = blockIdx.x * 256 + threadIdx.x;
    if (e >= E) return;
    int s = ei[e], d = ei[E + e];
    int pos = atomicAdd(&bcur[d >> BSHIFT], 1);
    int2 pk; pk.x = s; pk.y = d;
    staged[pos] = pk;
}

// Pass B: one workgroup per bucket; scatter into bucket's L2-local CSR window
__global__ __launch_bounds__(256) void place_kernel(const int2* __restrict__ staged,
                                                    const int* __restrict__ row_start,
                                                    const float* __restrict__ dis,
                                                    int2* __restrict__ csr_pk, int n) {
    int b = blockIdx.x;
    int nb = b << BSHIFT;
    int nodes = min(64, n - nb);
    __shared__ int cur[64];
    __shared__ float disl[64];
    int t = threadIdx.x;
    if (t < nodes) {
        cur[t] = row_start[nb + t] + 1;    // slot 0 = self loop
        disl[t] = dis[nb + t];
    }
    __syncthreads();
    int sbeg = row_start[nb] - nb;
    int nend = min(nb + 64, n);
    int send = row_start[nend] - nend;
    for (int i = sbeg + t; i < send; i += 256) {
        int2 e = staged[i];
        int s = e.x, d = e.y;
        float w = dis[s] * disl[d - nb];
        int pos = atomicAdd(&cur[d - nb], 1);
        int2 pk; pk.x = s; pk.y = __float_as_int(w);
        csr_pk[pos] = pk;
    }
}

// ---------------- bf16 MFMA GEMM: H[M x NOUT] = A[M x 128] * W[128 x NOUT] ----------
template <int NOUT>
__global__ __launch_bounds__(256) void gemm_bf16_kernel(const unsigned short* __restrict__ A,
                                                        const unsigned short* __restrict__ Wt,
                                                        unsigned short* __restrict__ H, int M) {
    int wave = (blockIdx.x * 256 + threadIdx.x) >> 6;
    int lane = threadIdx.x & 63;
    int m0 = wave << 4;
    if (m0 >= M) return;                  // M divisible by 16
    int m = lane & 15, q = lane >> 4;
    constexpr int NT = NOUT / 16;
    f32x4 acc[NT];
    #pragma unroll
    for (int t = 0; t < NT; t++) acc[t] = (f32x4){0.f, 0.f, 0.f, 0.f};
    const short8* Arow = (const short8*)(A + (size_t)(m0 + m) * 128);
    #pragma unroll
    for (int kk = 0; kk < 4; kk++) {
        short8 a = Arow[kk * 4 + q];      // A[m0+m][kk*32 + q*8 .. +7]
        #pragma unroll
        for (int t = 0; t < NT; t++) {
            const short8* Bp = (const short8*)(Wt + (size_t)(t * 16 + m) * 128);
            short8 b = Bp[kk * 4 + q];    // W[kk*32+q*8+j][t*16+m]
            acc[t] = __builtin_amdgcn_mfma_f32_16x16x32_bf16(a, b, acc[t], 0, 0, 0);
        }
    }
    #pragma unroll
    for (int t = 0; t < NT; t++)
        #pragma unroll
        for (int r = 0; r < 4; r++)
            H[(size_t)(m0 + q * 4 + r) * NOUT + t * 16 + m] = f2bf(acc[t][r]);
}

// ---------------- CSR aggregation (bf16 H, packed 8B edges) ----------------
template <int EPL, bool RELU, bool OUTBF>
__global__ __launch_bounds__(256) void aggregate_kernel(const unsigned short* __restrict__ H,
                                                        const int* __restrict__ row_start,
                                                        const int2* __restrict__ csr_pk,
                                                        const float* __restrict__ bias,
                                                        void* __restrict__ out, int n) {
    int wave = (blockIdx.x * 256 + threadIdx.x) >> 6;
    int lane = threadIdx.x & 63;
    if (wave >= n) return;
    constexpr int F = EPL * 64;
    int c = lane * EPL;
    float acc0 = 0.f, acc1 = 0.f;
    int p0 = row_start[wave], p1 = row_start[wave + 1];
    int p = p0;
    for (; p + 4 <= p1; p += 4) {
        int2 e0 = csr_pk[p],     e1 = csr_pk[p + 1];
        int2 e2 = csr_pk[p + 2], e3 = csr_pk[p + 3];
        float w0 = __int_as_float(e0.y), w1 = __int_as_float(e1.y);
        float w2 = __int_as_float(e2.y), w3 = __int_as_float(e3.y);
        if (EPL == 2) {
            unsigned int h0 = *(const unsigned int*)(H + (size_t)e0.x * F + c);
            unsigned int h1 = *(const unsigned int*)(H + (size_t)e1.x * F + c);
            unsigned int h2 = *(const unsigned int*)(H + (size_t)e2.x * F + c);
            unsigned int h3 = *(const unsigned int*)(H + (size_t)e3.x * F + c);
            acc0 += w0 * bflo(h0); acc1 += w0 * bfhi(h0);
            acc0 += w1 * bflo(h1); acc1 += w1 * bfhi(h1);
            acc0 += w2 * bflo(h2); acc1 += w2 * bfhi(h2);
            acc0 += w3 * bflo(h3); acc1 += w3 * bfhi(h3);
        } else {
            unsigned short h0 = H[(size_t)e0.x * F + c];
            unsigned short h1 = H[(size_t)e1.x * F + c];
            unsigned short h2 = H[(size_t)e2.x * F + c];
            unsigned short h3 = H[(size_t)e3.x * F + c];
            acc0 += w0 * __uint_as_float((unsigned int)h0 << 16);
            acc0 += w1 * __uint_as_float((unsigned int)h1 << 16);
            acc0 += w2 * __uint_as_float((unsigned int)h2 << 16);
            acc0 += w3 * __uint_as_float((unsigned int)h3 << 16);
        }
    }
    for (; p < p1; p++) {
        int2 e = csr_pk[p];
        float wgt = __int_as_float(e.y);
        if (EPL == 2) {
            unsigned int h = *(const unsigned int*)(H + (size_t)e.x * F + c);
            acc0 += wgt * bflo(h); acc1 += wgt * bfhi(h);
        } else {
            unsigned short h = H[(size_t)e.x * F + c];
            acc0 += wgt * __uint_as_float((unsigned int)h << 16);
        }
    }
    acc0 += bias[c];
    if (EPL == 2) acc1 += bias[c + 1];
    if (RELU) { acc0 = fmaxf(acc0, 0.f); if (EPL == 2) acc1 = fmaxf(acc1, 0.f); }
    if (OUTBF) {
        unsigned short* ob = (unsigned short*)out + (size_t)wave * F;
        if (EPL == 2) { ushort2 r; r.x = f2bf(acc0); r.y = f2bf(acc1); ((ushort2*)ob)[lane] = r; }
        else ob[c] = f2bf(acc0);
    } else {
        float* of = (float*)out + (size_t)wave * F;
        if (EPL == 2) { ((float2*)of)[lane] = make_float2(acc0, acc1); }
        else of[c] = acc0;
    }
}

// ---------------- decode: hidden = z[a]*z[b]; logits = sum; normalize ----------------
__global__ __launch_bounds__(256) void decode_kernel(const float* __restrict__ Z,
                                                     const int* __restrict__ eli, int EL,
                                                     float* __restrict__ out_h,
                                                     float* __restrict__ out_l) {
    int wave = (blockIdx.x * 256 + threadIdx.x) >> 6;
    int lane = threadIdx.x & 63;
    if (wave >= EL) return;
    int a = eli[wave], b = eli[EL + wave];
    float h = Z[(size_t)a * 64 + lane] * Z[(size_t)b * 64 + lane];
    float s = h, ss = h * h;
    #pragma unroll
    for (int off = 32; off > 0; off >>= 1) {
        s  += __shfl_xor(s, off, 64);
        ss += __shfl_xor(ss, off, 64);
    }
    float nrm = fmaxf(sqrtf(ss), 1e-12f);
    out_h[(size_t)wave * 64 + lane] = h / nrm;
    if (lane == 0) out_l[wave] = s;
}

extern "C" void kernel_launch(void* const* d_in, const int* in_sizes, int n_in,
                              void* d_out, int out_size, void* d_ws, size_t ws_size,
                              hipStream_t stream) {
    const float* x  = (const float*)d_in[0];
    const float* W1 = (const float*)d_in[1];
    const float* b1 = (const float*)d_in[2];
    const float* W2 = (const float*)d_in[3];
    const float* b2 = (const float*)d_in[4];
    const float* W3 = (const float*)d_in[5];
    const float* b3 = (const float*)d_in[6];
    const int* edge_index = (const int*)d_in[7];
    const int* eli        = (const int*)d_in[8];

    const int N  = in_sizes[0] / DIN;
    const int E  = in_sizes[7] / 2;
    const int EL = in_sizes[8] / 2;
    const int NBUK = (N + 63) >> BSHIFT;

    char* w = (char*)d_ws;
    auto alloc = [&](size_t bytes) -> char* {
        char* p = w; w += (bytes + 255) & ~(size_t)255; return p;
    };
    unsigned short* bufA  = (unsigned short*)alloc((size_t)N * DH * 2);  // H1/H2/H3 (bf16)
    float*          Z3    = (float*)alloc((size_t)N * DOUT * 4);         // fp32 final embeddings
    unsigned short* Xbf   = (unsigned short*)alloc((size_t)N * DH * 2);  // bf16 activations
    unsigned short* Wt1   = (unsigned short*)alloc(128 * 128 * 2);
    unsigned short* Wt2   = (unsigned short*)alloc(128 * 128 * 2);
    unsigned short* Wt3   = (unsigned short*)alloc(64 * 128 * 2);
    int*            deg   = (int*)alloc((size_t)N * 4);
    int*            row_start = (int*)alloc((size_t)(N + 1) * 4);
    float*          dis    = (float*)alloc((size_t)N * 4);
    int*            bsum   = (int*)alloc(1024);
    int*            bcur   = (int*)alloc((size_t)(NBUK + 1) * 4);
    int2*           csr_pk = (int2*)alloc((size_t)(E + N) * 8);
    int2*           staged = (int2*)bufA;    // alias: bufA unused until gemm1 (E*8 <= N*DH*2)

    float* out_h = (float*)d_out;
    float* out_l = out_h + (size_t)EL * DOUT;

    const int NB = (N + 1023) / 1024;   // scan blocks (98 for N=100000, <=256 required)

    // --- preprocessing ---
    cast_bf16_kernel<<<(N * DIN / 4 + 255) / 256, 256, 0, stream>>>(x, Xbf, N * DIN / 4);
    prep_w_kernel<<<64, 256, 0, stream>>>(W1, W2, W3, Wt1, Wt2, Wt3);
    deg_init_kernel<<<(N + 255) / 256, 256, 0, stream>>>(deg, N);
    deg_count_kernel<<<(E + 255) / 256, 256, 0, stream>>>(edge_index, E, deg);
    scan_block_sums<<<NB, 256, 0, stream>>>(deg, bsum, N);
    scan_bsum_kernel<<<1, 256, 0, stream>>>(bsum, NB);
    scan_final_kernel<<<NB, 256, 0, stream>>>(deg, bsum, row_start, dis, csr_pk, N);
    bcur_init_kernel<<<(NBUK + 256) / 256, 256, 0, stream>>>(row_start, bcur, NBUK, N);
    stage_kernel<<<(E + 255) / 256, 256, 0, stream>>>(edge_index, E, bcur, staged);
    place_kernel<<<NBUK, 256, 0, stream>>>(staged, row_start, dis, csr_pk, N);

    const int gemm_grid = ((N / 16) * 64 + 255) / 256;
    const int agg_grid  = (N + 3) / 4;

    // --- layer 1 ---
    gemm_bf16_kernel<128><<<gemm_grid, 256, 0, stream>>>(Xbf, Wt1, bufA, N);
    aggregate_kernel<2, true, true><<<agg_grid, 256, 0, stream>>>(bufA, row_start, csr_pk, b1, Xbf, N);
    // --- layer 2 ---
    gemm_bf16_kernel<128><<<gemm_grid, 256, 0, stream>>>(Xbf, Wt2, bufA, N);
    aggregate_kernel<2, true, true><<<agg_grid, 256, 0, stream>>>(bufA, row_start, csr_pk, b2, Xbf, N);
    // --- layer 3 ---
    gemm_bf16_kernel<64><<<gemm_grid, 256, 0, stream>>>(Xbf, Wt3, bufA, N);
    aggregate_kernel<1, false, false><<<agg_grid, 256, 0, stream>>>(bufA, row_start, csr_pk, b3, Z3, N);
    // --- decode ---
    decode_kernel<<<(EL + 3) / 4, 256, 0, stream>>>(Z3, eli, EL, out_h, out_l);
}

// Round 7
// 635.329 us; speedup vs baseline: 1.2690x; 1.2690x over previous
//
#include <hip/hip_runtime.h>
#include <hip/hip_bf16.h>

#define DIN 128
#define DH  128
#define DOUT 64
#define PAD 16                   // one atomic counter per 64B line

typedef __attribute__((ext_vector_type(8))) short short8;
typedef __attribute__((ext_vector_type(4))) float f32x4;

static __device__ __forceinline__ unsigned short f2bf(float f) {
    unsigned int u = __float_as_uint(f);
    u += 0x7FFFu + ((u >> 16) & 1u);   // RNE
    return (unsigned short)(u >> 16);
}
static __device__ __forceinline__ float bflo(unsigned int p) {
    return __uint_as_float(p << 16);
}
static __device__ __forceinline__ float bfhi(unsigned int p) {
    return __uint_as_float(p & 0xFFFF0000u);
}

// ---------------- weights: transpose + cast to bf16 ----------------
__global__ __launch_bounds__(256) void prep_w_kernel(const float* __restrict__ W1,
                                                     const float* __restrict__ W2,
                                                     const float* __restrict__ W3,
                                                     unsigned short* __restrict__ Wt1,
                                                     unsigned short* __restrict__ Wt2,
                                                     unsigned short* __restrict__ Wt3) {
    int i = blockIdx.x * 256 + threadIdx.x;
    if (i < 128 * 128) {
        int n = i >> 7, k = i & 127;
        Wt1[n * 128 + k] = f2bf(W1[k * 128 + n]);
        Wt2[n * 128 + k] = f2bf(W2[k * 128 + n]);
        if (n < 64) Wt3[n * 128 + k] = f2bf(W3[k * 64 + n]);
    }
}

// ---------------- degree (padded counters: deg_p[i*PAD]) ----------------
__global__ __launch_bounds__(256) void deg_init_kernel(int* __restrict__ deg_p, int n) {
    int i = blockIdx.x * 256 + threadIdx.x;
    if (i < n) deg_p[(size_t)i * PAD] = 1;   // self-loop
}
__global__ __launch_bounds__(256) void deg_count_kernel(const int* __restrict__ ei, int E,
                                                        int* __restrict__ deg_p) {
    int e = blockIdx.x * 256 + threadIdx.x;
    if (e >= E) return;
    atomicAdd(&deg_p[(size_t)ei[E + e] * PAD], 1);   // dst
}

// ---------------- 3-phase exclusive scan of deg -> row_start ----------------
__global__ __launch_bounds__(256) void scan_block_sums(const int* __restrict__ deg_p,
                                                       int* __restrict__ bsum, int n) {
    __shared__ int s[256];
    int t = threadIdx.x, base = blockIdx.x * 1024;
    int v = 0;
    #pragma unroll
    for (int j = 0; j < 4; j++) {
        int idx = base + t * 4 + j;
        if (idx < n) v += deg_p[(size_t)idx * PAD];
    }
    s[t] = v; __syncthreads();
    for (int off = 128; off > 0; off >>= 1) {
        if (t < off) s[t] += s[t + off];
        __syncthreads();
    }
    if (t == 0) bsum[blockIdx.x] = s[0];
}

__global__ __launch_bounds__(256) void scan_bsum_kernel(int* __restrict__ bsum, int nb) {
    __shared__ int s[256];
    int t = threadIdx.x;
    s[t] = (t < nb) ? bsum[t] : 0; __syncthreads();
    for (int off = 1; off < 256; off <<= 1) {
        int v = (t >= off) ? s[t - off] : 0;
        __syncthreads();
        s[t] += v;
        __syncthreads();
    }
    if (t < nb) bsum[t] = (t > 0) ? s[t - 1] : 0;   // exclusive
}

__global__ __launch_bounds__(256) void scan_final_kernel(const int* __restrict__ deg_p,
                                                         const int* __restrict__ bsum_ex,
                                                         int* __restrict__ row_start,
                                                         float* __restrict__ dis,
                                                         int* __restrict__ cursor_p,
                                                         int2* __restrict__ csr_pk, int n) {
    __shared__ int s[256];
    int t = threadIdx.x, base = blockIdx.x * 1024;
    int d[4]; int local = 0;
    #pragma unroll
    for (int j = 0; j < 4; j++) {
        int idx = base + t * 4 + j;
        d[j] = (idx < n) ? deg_p[(size_t)idx * PAD] : 0;
        local += d[j];
    }
    s[t] = local; __syncthreads();
    for (int off = 1; off < 256; off <<= 1) {
        int v = (t >= off) ? s[t - off] : 0;
        __syncthreads();
        s[t] += v;
        __syncthreads();
    }
    int ex = ((t > 0) ? s[t - 1] : 0) + bsum_ex[blockIdx.x];
    #pragma unroll
    for (int j = 0; j < 4; j++) {
        int idx = base + t * 4 + j;
        if (idx < n) {
            row_start[idx] = ex;
            float di = rsqrtf((float)d[j]);
            dis[idx] = di;
            cursor_p[(size_t)idx * PAD] = ex + 1;   // slot 0 = self loop
            int2 pk; pk.x = idx; pk.y = __float_as_int(di * di);
            csr_pk[ex] = pk;
            if (idx == n - 1) row_start[n] = ex + d[j];
            ex += d[j];
        }
    }
}

// ---------------- counting-sort edges into CSR (packed 8B entry, 1 edge/thread) ----
__global__ __launch_bounds__(256) void csr_fill_kernel(const int* __restrict__ ei, int E,
                                                       const float* __restrict__ dis,
                                                       int* __restrict__ cursor_p,
                                                       int2* __restrict__ csr_pk) {
    int e = blockIdx.x * 256 + threadIdx.x;
    if (e >= E) return;
    int s = ei[e], d = ei[E + e];
    int pos = atomicAdd(&cursor_p[(size_t)d * PAD], 1);
    int2 pk; pk.x = s; pk.y = __float_as_int(dis[s] * dis[d]);
    csr_pk[pos] = pk;
}

// ---------------- bf16 MFMA GEMM: H[M x NOUT] = A[M x 128] * W[128 x NOUT] ----------
// AFP32: A is fp32 (layer 1 reads x directly, converts in-register)
template <int NOUT, bool AFP32>
__global__ __launch_bounds__(256) void gemm_bf16_kernel(const void* __restrict__ Av,
                                                        const unsigned short* __restrict__ Wt,
                                                        unsigned short* __restrict__ H, int M) {
    int wave = (blockIdx.x * 256 + threadIdx.x) >> 6;
    int lane = threadIdx.x & 63;
    int m0 = wave << 4;
    if (m0 >= M) return;                  // M divisible by 16
    int m = lane & 15, q = lane >> 4;
    constexpr int NT = NOUT / 16;
    f32x4 acc[NT];
    #pragma unroll
    for (int t = 0; t < NT; t++) acc[t] = (f32x4){0.f, 0.f, 0.f, 0.f};
    const short8* Arow = (const short8*)((const unsigned short*)Av + (size_t)(m0 + m) * 128);
    const float*  Arow32 = (const float*)Av + (size_t)(m0 + m) * 128;
    #pragma unroll
    for (int kk = 0; kk < 4; kk++) {
        short8 a;
        if (AFP32) {
            float4 u = *(const float4*)(Arow32 + kk * 32 + q * 8);
            float4 v = *(const float4*)(Arow32 + kk * 32 + q * 8 + 4);
            a[0] = (short)f2bf(u.x); a[1] = (short)f2bf(u.y);
            a[2] = (short)f2bf(u.z); a[3] = (short)f2bf(u.w);
            a[4] = (short)f2bf(v.x); a[5] = (short)f2bf(v.y);
            a[6] = (short)f2bf(v.z); a[7] = (short)f2bf(v.w);
        } else {
            a = Arow[kk * 4 + q];         // A[m0+m][kk*32 + q*8 .. +7]
        }
        #pragma unroll
        for (int t = 0; t < NT; t++) {
            const short8* Bp = (const short8*)(Wt + (size_t)(t * 16 + m) * 128);
            short8 b = Bp[kk * 4 + q];    // W[kk*32+q*8+j][t*16+m]
            acc[t] = __builtin_amdgcn_mfma_f32_16x16x32_bf16(a, b, acc[t], 0, 0, 0);
        }
    }
    #pragma unroll
    for (int t = 0; t < NT; t++)
        #pragma unroll
        for (int r = 0; r < 4; r++)
            H[(size_t)(m0 + q * 4 + r) * NOUT + t * 16 + m] = f2bf(acc[t][r]);
}

// ---------------- CSR aggregation (bf16 H, packed 8B edges) ----------------
template <int EPL, bool RELU, bool OUTBF>
__global__ __launch_bounds__(256) void aggregate_kernel(const unsigned short* __restrict__ H,
                                                        const int* __restrict__ row_start,
                                                        const int2* __restrict__ csr_pk,
                                                        const float* __restrict__ bias,
                                                        void* __restrict__ out, int n) {
    int wave = (blockIdx.x * 256 + threadIdx.x) >> 6;
    int lane = threadIdx.x & 63;
    if (wave >= n) return;
    constexpr int F = EPL * 64;
    int c = lane * EPL;
    float acc0 = 0.f, acc1 = 0.f;
    int p0 = row_start[wave], p1 = row_start[wave + 1];
    int p = p0;
    for (; p + 4 <= p1; p += 4) {
        int2 e0 = csr_pk[p],     e1 = csr_pk[p + 1];
        int2 e2 = csr_pk[p + 2], e3 = csr_pk[p + 3];
        float w0 = __int_as_float(e0.y), w1 = __int_as_float(e1.y);
        float w2 = __int_as_float(e2.y), w3 = __int_as_float(e3.y);
        if (EPL == 2) {
            unsigned int h0 = *(const unsigned int*)(H + (size_t)e0.x * F + c);
            unsigned int h1 = *(const unsigned int*)(H + (size_t)e1.x * F + c);
            unsigned int h2 = *(const unsigned int*)(H + (size_t)e2.x * F + c);
            unsigned int h3 = *(const unsigned int*)(H + (size_t)e3.x * F + c);
            acc0 += w0 * bflo(h0); acc1 += w0 * bfhi(h0);
            acc0 += w1 * bflo(h1); acc1 += w1 * bfhi(h1);
            acc0 += w2 * bflo(h2); acc1 += w2 * bfhi(h2);
            acc0 += w3 * bflo(h3); acc1 += w3 * bfhi(h3);
        } else {
            unsigned short h0 = H[(size_t)e0.x * F + c];
            unsigned short h1 = H[(size_t)e1.x * F + c];
            unsigned short h2 = H[(size_t)e2.x * F + c];
            unsigned short h3 = H[(size_t)e3.x * F + c];
            acc0 += w0 * __uint_as_float((unsigned int)h0 << 16);
            acc0 += w1 * __uint_as_float((unsigned int)h1 << 16);
            acc0 += w2 * __uint_as_float((unsigned int)h2 << 16);
            acc0 += w3 * __uint_as_float((unsigned int)h3 << 16);
        }
    }
    for (; p < p1; p++) {
        int2 e = csr_pk[p];
        float wgt = __int_as_float(e.y);
        if (EPL == 2) {
            unsigned int h = *(const unsigned int*)(H + (size_t)e.x * F + c);
            acc0 += wgt * bflo(h); acc1 += wgt * bfhi(h);
        } else {
            unsigned short h = H[(size_t)e.x * F + c];
            acc0 += wgt * __uint_as_float((unsigned int)h << 16);
        }
    }
    acc0 += bias[c];
    if (EPL == 2) acc1 += bias[c + 1];
    if (RELU) { acc0 = fmaxf(acc0, 0.f); if (EPL == 2) acc1 = fmaxf(acc1, 0.f); }
    if (OUTBF) {
        unsigned short* ob = (unsigned short*)out + (size_t)wave * F;
        if (EPL == 2) { ushort2 r; r.x = f2bf(acc0); r.y = f2bf(acc1); ((ushort2*)ob)[lane] = r; }
        else ob[c] = f2bf(acc0);
    } else {
        float* of = (float*)out + (size_t)wave * F;
        if (EPL == 2) { ((float2*)of)[lane] = make_float2(acc0, acc1); }
        else of[c] = acc0;
    }
}

// ---------------- decode: hidden = z[a]*z[b]; logits = sum; normalize ----------------
__global__ __launch_bounds__(256) void decode_kernel(const float* __restrict__ Z,
                                                     const int* __restrict__ eli, int EL,
                                                     float* __restrict__ out_h,
                                                     float* __restrict__ out_l) {
    int wave = (blockIdx.x * 256 + threadIdx.x) >> 6;
    int lane = threadIdx.x & 63;
    if (wave >= EL) return;
    int a = eli[wave], b = eli[EL + wave];
    float h = Z[(size_t)a * 64 + lane] * Z[(size_t)b * 64 + lane];
    float s = h, ss = h * h;
    #pragma unroll
    for (int off = 32; off > 0; off >>= 1) {
        s  += __shfl_xor(s, off, 64);
        ss += __shfl_xor(ss, off, 64);
    }
    float nrm = fmaxf(sqrtf(ss), 1e-12f);
    out_h[(size_t)wave * 64 + lane] = h / nrm;
    if (lane == 0) out_l[wave] = s;
}

extern "C" void kernel_launch(void* const* d_in, const int* in_sizes, int n_in,
                              void* d_out, int out_size, void* d_ws, size_t ws_size,
                              hipStream_t stream) {
    const float* x  = (const float*)d_in[0];
    const float* W1 = (const float*)d_in[1];
    const float* b1 = (const float*)d_in[2];
    const float* W2 = (const float*)d_in[3];
    const float* b2 = (const float*)d_in[4];
    const float* W3 = (const float*)d_in[5];
    const float* b3 = (const float*)d_in[6];
    const int* edge_index = (const int*)d_in[7];
    const int* eli        = (const int*)d_in[8];

    const int N  = in_sizes[0] / DIN;
    const int E  = in_sizes[7] / 2;
    const int EL = in_sizes[8] / 2;

    char* w = (char*)d_ws;
    auto alloc = [&](size_t bytes) -> char* {
        char* p = w; w += (bytes + 255) & ~(size_t)255; return p;
    };
    unsigned short* bufA  = (unsigned short*)alloc((size_t)N * DH * 2);  // H1/H2/H3 (bf16)
    float*          Z3    = (float*)alloc((size_t)N * DOUT * 4);         // fp32 final embeddings
    unsigned short* Xbf   = (unsigned short*)alloc((size_t)N * DH * 2);  // bf16 activations
    unsigned short* Wt1   = (unsigned short*)alloc(128 * 128 * 2);
    unsigned short* Wt2   = (unsigned short*)alloc(128 * 128 * 2);
    unsigned short* Wt3   = (unsigned short*)alloc(64 * 128 * 2);
    int*            deg_p = (int*)alloc((size_t)N * PAD * 4);            // padded counters
    int*            row_start = (int*)alloc((size_t)(N + 1) * 4);
    int*            cursor_p = (int*)alloc((size_t)N * PAD * 4);         // padded cursors
    float*          dis    = (float*)alloc((size_t)N * 4);
    int*            bsum   = (int*)alloc(1024);
    int2*           csr_pk = (int2*)alloc((size_t)(E + N) * 8);

    float* out_h = (float*)d_out;
    float* out_l = out_h + (size_t)EL * DOUT;

    const int NB = (N + 1023) / 1024;   // scan blocks (98 for N=100000, <=256 required)

    // --- build CSR ---
    prep_w_kernel<<<64, 256, 0, stream>>>(W1, W2, W3, Wt1, Wt2, Wt3);
    deg_init_kernel<<<(N + 255) / 256, 256, 0, stream>>>(deg_p, N);
    deg_count_kernel<<<(E + 255) / 256, 256, 0, stream>>>(edge_index, E, deg_p);
    scan_block_sums<<<NB, 256, 0, stream>>>(deg_p, bsum, N);
    scan_bsum_kernel<<<1, 256, 0, stream>>>(bsum, NB);
    scan_final_kernel<<<NB, 256, 0, stream>>>(deg_p, bsum, row_start, dis, cursor_p, csr_pk, N);
    csr_fill_kernel<<<(E + 255) / 256, 256, 0, stream>>>(edge_index, E, dis, cursor_p, csr_pk);

    const int gemm_grid = ((N / 16) * 64 + 255) / 256;
    const int agg_grid  = (N + 3) / 4;

    // --- layer 1 (reads fp32 x directly) ---
    gemm_bf16_kernel<128, true><<<gemm_grid, 256, 0, stream>>>(x, Wt1, bufA, N);
    aggregate_kernel<2, true, true><<<agg_grid, 256, 0, stream>>>(bufA, row_start, csr_pk, b1, Xbf, N);
    // --- layer 2 ---
    gemm_bf16_kernel<128, false><<<gemm_grid, 256, 0, stream>>>(Xbf, Wt2, bufA, N);
    aggregate_kernel<2, true, true><<<agg_grid, 256, 0, stream>>>(bufA, row_start, csr_pk, b2, Xbf, N);
    // --- layer 3 ---
    gemm_bf16_kernel<64, false><<<gemm_grid, 256, 0, stream>>>(Xbf, Wt3, bufA, N);
    aggregate_kernel<1, false, false><<<agg_grid, 256, 0, stream>>>(bufA, row_start, csr_pk, b3, Z3, N);
    // --- decode ---
    decode_kernel<<<(EL + 3) / 4, 256, 0, stream>>>(Z3, eli, EL, out_h, out_l);
}